// Round 2
// baseline (3462.371 us; speedup 1.0000x reference)
//
#include <hip/hip_runtime.h>

#define G 128
#define N 32
#define H 128
#define L 6

// ---------------------------------------------------------------------------
// E1: P0 = emb_x @ W0 + b0, P1 = emb_x @ W1 + b1. grid=2.
// ---------------------------------------------------------------------------
__global__ __launch_bounds__(256) void k_emb_mm(
    const float* __restrict__ emb_x,
    const float* __restrict__ W0, const float* __restrict__ b0, float* __restrict__ P0,
    const float* __restrict__ W1, const float* __restrict__ b1, float* __restrict__ P1) {
  const float* W = blockIdx.x ? W1 : W0;
  const float* b = blockIdx.x ? b1 : b0;
  float*       P = blockIdx.x ? P1 : P0;
  __shared__ float embs_t[128 * 32];   // [k][i]
  int tid = threadIdx.x;
  {
    int i = tid & 31, k0 = (tid >> 5) * 16;
    const float* src = emb_x + i * 128 + k0;
#pragma unroll
    for (int m = 0; m < 16; m++) embs_t[(k0 + m) * 32 + i] = src[m];
  }
  __syncthreads();
  int i  = tid >> 3;
  int h0 = (tid & 7) * 16;
  float acc[16];
#pragma unroll
  for (int hh = 0; hh < 16; hh++) acc[hh] = b[h0 + hh];
  for (int k = 0; k < 128; k++) {
    float a = embs_t[k * 32 + i];
    const float4* wr = (const float4*)(W + k * 128 + h0);
    float4 w0 = wr[0], w1 = wr[1], w2 = wr[2], w3 = wr[3];
    acc[0]  += a * w0.x; acc[1]  += a * w0.y; acc[2]  += a * w0.z; acc[3]  += a * w0.w;
    acc[4]  += a * w1.x; acc[5]  += a * w1.y; acc[6]  += a * w1.z; acc[7]  += a * w1.w;
    acc[8]  += a * w2.x; acc[9]  += a * w2.y; acc[10] += a * w2.z; acc[11] += a * w2.w;
    acc[12] += a * w3.x; acc[13] += a * w3.y; acc[14] += a * w3.z; acc[15] += a * w3.w;
  }
  float4* dst = (float4*)(P + i * 128 + h0);
  dst[0] = make_float4(acc[0], acc[1], acc[2], acc[3]);
  dst[1] = make_float4(acc[4], acc[5], acc[6], acc[7]);
  dst[2] = make_float4(acc[8], acc[9], acc[10], acc[11]);
  dst[3] = make_float4(acc[12], acc[13], acc[14], acc[15]);
}

// ---------------------------------------------------------------------------
// E2: build X h-planar: Xp[g][h][i*32+j]. One WG per graph.
// ---------------------------------------------------------------------------
__global__ __launch_bounds__(256) void k_buildX(
    const int* __restrict__ x_idx, const int* __restrict__ tf_idx,
    const float* __restrict__ P0, const float* __restrict__ P1,
    const float* __restrict__ emb_tf, float* __restrict__ Xp) {
  int g = blockIdx.x, tid = threadIdx.x;
  __shared__ float x0t[128 * 32];
  __shared__ float x1t[128 * 32];
  __shared__ float etf[128 * 16];
  __shared__ int   tfs[1024];
  {
    int i = tid & 31, h0 = (tid >> 5) * 16;
    int r = x_idx[g * 32 + i];
    const float* s0 = P0 + r * 128 + h0;
    const float* s1 = P1 + r * 128 + h0;
#pragma unroll
    for (int m = 0; m < 16; m++) {
      x0t[(h0 + m) * 32 + i] = s0[m];
      x1t[(h0 + m) * 32 + i] = s1[m];
    }
  }
  {
    int t = tid & 15, h0 = (tid >> 4) * 8;
    const float* s = emb_tf + t * 128 + h0;
#pragma unroll
    for (int m = 0; m < 8; m++) etf[(h0 + m) * 16 + t] = s[m];
  }
  ((int4*)tfs)[tid] = ((const int4*)(tf_idx + (size_t)g * 1024))[tid];
  __syncthreads();
  int i = tid >> 3, j0 = (tid & 7) * 4;
  int t0 = tfs[i * 32 + j0 + 0], t1 = tfs[i * 32 + j0 + 1];
  int t2 = tfs[i * 32 + j0 + 2], t3 = tfs[i * 32 + j0 + 3];
  float* outg = Xp + ((size_t)g << 17);
  for (int h = 0; h < 128; h++) {
    float a = x0t[h * 32 + i];
    const float* x1r = x1t + h * 32;
    const float* er  = etf + h * 16;
    float4 v;
    v.x = a * x1r[j0 + 0] * er[t0];
    v.y = a * x1r[j0 + 1] * er[t1];
    v.z = a * x1r[j0 + 2] * er[t2];
    v.w = a * x1r[j0 + 3] * er[t3];
    *(float4*)(outg + h * 1024 + tid * 4) = v;
  }
}

// ---------------------------------------------------------------------------
// K1 v3: tXp = relu(LN(X @ Wc[l] + bc[l])), h-planar.
// 256 pos x 128 h per WG (grid G*4), 16x8 thread tile (128 acc), K=128 in
// 8 chunks of 16, double-buffered LDS staging with ONE barrier per chunk.
// LDS inner-loop traffic: 6 b128 per 256 FLOP = 0.375 B/FLOP (below pipe).
// ---------------------------------------------------------------------------
__global__ __launch_bounds__(256, 2) void k_conv_mlp(
    const float* __restrict__ Xp, const float* __restrict__ W,
    const float* __restrict__ bcl, const float* __restrict__ gcl,
    const float* __restrict__ ccl, float* __restrict__ tXp) {
  int g = blockIdx.x >> 2, qb = blockIdx.x & 3;
  int tid = threadIdx.x;
  __shared__ float Xs[2][16 * 260];
  __shared__ float Ws[2][16 * 132];
  __shared__ float red[256 * 17];
  __shared__ float stat[256];
  int pt = tid & 15, ht = tid >> 4;
  int p0 = pt * 4, h0 = ht * 4;
  float bcv[8], gcv[8], ccv[8];
#pragma unroll
  for (int hi = 0; hi < 8; hi++) {
    int hcol = h0 + (hi & 3) + (hi >> 2) * 64;
    bcv[hi] = bcl[hcol]; gcv[hi] = gcl[hcol]; ccv[hi] = ccl[hcol];
  }
  float acc[16][8];
#pragma unroll
  for (int pi = 0; pi < 16; pi++)
#pragma unroll
    for (int hi = 0; hi < 8; hi++) acc[pi][hi] = bcv[hi];

  const float* Xg = Xp + ((size_t)g << 17) + qb * 256;
  int lrow = tid >> 4, xc = (tid & 15) * 16, wc = (tid & 15) * 8;
  float4 xr[4], wr[2];
  {  // prologue: stage chunk 0
    const float* xsrc = Xg + (size_t)lrow * 1024 + xc;
#pragma unroll
    for (int m = 0; m < 4; m++) xr[m] = ((const float4*)xsrc)[m];
    const float* wsrc = W + lrow * 128 + wc;
    wr[0] = ((const float4*)wsrc)[0]; wr[1] = ((const float4*)wsrc)[1];
#pragma unroll
    for (int m = 0; m < 4; m++) *(float4*)&Xs[0][lrow * 260 + xc + 4 * m] = xr[m];
    *(float4*)&Ws[0][lrow * 132 + wc]     = wr[0];
    *(float4*)&Ws[0][lrow * 132 + wc + 4] = wr[1];
  }
  __syncthreads();
#pragma unroll 1
  for (int kb = 0; kb < 8; kb++) {
    int cur = kb & 1;
    if (kb < 7) {  // prefetch next chunk to regs (overlaps compute)
      const float* xsrc = Xg + (size_t)((kb + 1) * 16 + lrow) * 1024 + xc;
#pragma unroll
      for (int m = 0; m < 4; m++) xr[m] = ((const float4*)xsrc)[m];
      const float* wsrc = W + ((kb + 1) * 16 + lrow) * 128 + wc;
      wr[0] = ((const float4*)wsrc)[0]; wr[1] = ((const float4*)wsrc)[1];
    }
#pragma unroll
    for (int kk = 0; kk < 16; kk++) {
      const float* xrow = &Xs[cur][kk * 260];
      const float* wrow = &Ws[cur][kk * 132];
      float av[16], wv[8];
#pragma unroll
      for (int m = 0; m < 4; m++) *(float4*)&av[4 * m] = *(const float4*)&xrow[p0 + 64 * m];
      *(float4*)&wv[0] = *(const float4*)&wrow[h0];
      *(float4*)&wv[4] = *(const float4*)&wrow[h0 + 64];
#pragma unroll
      for (int pi = 0; pi < 16; pi++)
#pragma unroll
        for (int hi = 0; hi < 8; hi++) acc[pi][hi] += av[pi] * wv[hi];
    }
    if (kb < 7) {  // write other buffer: safe, nobody reads it this iter
      int nxt = cur ^ 1;
#pragma unroll
      for (int m = 0; m < 4; m++) *(float4*)&Xs[nxt][lrow * 260 + xc + 4 * m] = xr[m];
      *(float4*)&Ws[nxt][lrow * 132 + wc]     = wr[0];
      *(float4*)&Ws[nxt][lrow * 132 + wc + 4] = wr[1];
    }
    __syncthreads();
  }
  // ---- LN pass A: mean over h (per position, two-pass for stability) ----
#pragma unroll
  for (int pi = 0; pi < 16; pi++) {
    int p = p0 + (pi & 3) + (pi >> 2) * 64;
    float s = 0.f;
#pragma unroll
    for (int hi = 0; hi < 8; hi++) s += acc[pi][hi];
    red[p * 17 + ht] = s;
  }
  __syncthreads();
  {
    float s = 0.f;
#pragma unroll
    for (int t = 0; t < 16; t++) s += red[tid * 17 + t];
    stat[tid] = s * (1.f / 128.f);
  }
  __syncthreads();
  float mv[16];
#pragma unroll
  for (int pi = 0; pi < 16; pi++) mv[pi] = stat[p0 + (pi & 3) + (pi >> 2) * 64];
  // ---- LN pass B: variance ----
#pragma unroll
  for (int pi = 0; pi < 16; pi++) {
    int p = p0 + (pi & 3) + (pi >> 2) * 64;
    float q = 0.f;
#pragma unroll
    for (int hi = 0; hi < 8; hi++) { float d = acc[pi][hi] - mv[pi]; q += d * d; }
    red[p * 17 + ht] = q;
  }
  __syncthreads();
  {
    float s = 0.f;
#pragma unroll
    for (int t = 0; t < 16; t++) s += red[tid * 17 + t];
    stat[tid] = rsqrtf(s * (1.f / 128.f) + 1e-5f);
  }
  __syncthreads();
  float rv[16];
#pragma unroll
  for (int pi = 0; pi < 16; pi++) rv[pi] = stat[p0 + (pi & 3) + (pi >> 2) * 64];
  // ---- normalize + relu + store ----
#pragma unroll
  for (int hi = 0; hi < 8; hi++) {
    int hcol = h0 + (hi & 3) + (hi >> 2) * 64;
    float* dst = tXp + (((size_t)(g * 128 + hcol)) << 10) + qb * 256;
#pragma unroll
    for (int q = 0; q < 4; q++) {
      int b = q * 4;
      float4 v;
      v.x = fmaxf((acc[b + 0][hi] - mv[b + 0]) * rv[b + 0] * gcv[hi] + ccv[hi], 0.f);
      v.y = fmaxf((acc[b + 1][hi] - mv[b + 1]) * rv[b + 1] * gcv[hi] + ccv[hi], 0.f);
      v.z = fmaxf((acc[b + 2][hi] - mv[b + 2]) * rv[b + 2] * gcv[hi] + ccv[hi], 0.f);
      v.w = fmaxf((acc[b + 3][hi] - mv[b + 3]) * rv[b + 3] * gcv[hi] + ccv[hi], 0.f);
      *(float4*)&dst[p0 + q * 64] = v;
    }
  }
}

// ---------------------------------------------------------------------------
// K2 v3: X[g,h,i,j] += sum_k tX[g,i,k,h] * (emb_ea[ea[g,k,j],h]*adj[g,k,j]).
// 8 h-planes per WG (grid G*16), 2 per wave sequentially (wave-local LDS,
// DS in-order => no barriers in the plane loop). tX staged row-major (pad 36,
// vector copies, NO transpose); A built from packed codes c=adj?ea:16 with
// one uchar4 read + 4 gathers + 1 b128 write per quad. 4x4 lane tile,
// k-blocked by 4: 8 b128 per 128 FLOP.
// ---------------------------------------------------------------------------
__global__ __launch_bounds__(256, 4) void k_conv_msg(
    const float* __restrict__ tXp, const int* __restrict__ ea_idx,
    const int* __restrict__ adj, const float* __restrict__ emb_ea,
    float* __restrict__ Xp) {
  int g  = blockIdx.x >> 4;
  int hb = (blockIdx.x & 15) * 8;
  int tid = threadIdx.x, wv = tid >> 6, lane = tid & 63;
  __shared__ unsigned char c8[1024];
  __shared__ float eacs[8][20];
  __shared__ __align__(16) float tXs[4][32 * 36];
  __shared__ __align__(16) float As[4][32 * 36];
  {
    int4 ev = ((const int4*)(ea_idx + (size_t)g * 1024))[tid];
    int4 av = ((const int4*)(adj   + (size_t)g * 1024))[tid];
    uchar4 c;
    c.x = av.x ? (unsigned char)ev.x : (unsigned char)16;
    c.y = av.y ? (unsigned char)ev.y : (unsigned char)16;
    c.z = av.z ? (unsigned char)ev.z : (unsigned char)16;
    c.w = av.w ? (unsigned char)ev.w : (unsigned char)16;
    ((uchar4*)c8)[tid] = c;
  }
  if (tid < 128) {
    int hh = tid >> 4, e = tid & 15;
    eacs[hh][e] = emb_ea[e * 128 + hb + hh];
  }
  if (tid >= 128 && tid < 136) eacs[tid - 128][16] = 0.f;
  __syncthreads();
  int i0 = (lane >> 3) * 4, j0 = (lane & 7) * 4;
  float* tw = tXs[wv];
  float* aw = As[wv];
#pragma unroll 1
  for (int pl = 0; pl < 2; pl++) {
    int hh = wv * 2 + pl;
    int h  = hb + hh;
    // stage tX plane (row-major, pad 36)
    const float4* tp = (const float4*)(tXp + (((size_t)(g * 128 + h)) << 10));
#pragma unroll
    for (int m = 0; m < 4; m++) {
      int f = lane + 64 * m;
      float4 v = tp[f];
      *(float4*)&tw[(f >> 3) * 36 + (f & 7) * 4] = v;
    }
    // build A[k][j] = eacs[hh][c8[k*32+j]]
#pragma unroll
    for (int m = 0; m < 4; m++) {
      int qd = lane + 64 * m;
      uchar4 cc = ((const uchar4*)c8)[qd];
      float4 a;
      a.x = eacs[hh][cc.x]; a.y = eacs[hh][cc.y];
      a.z = eacs[hh][cc.z]; a.w = eacs[hh][cc.w];
      *(float4*)&aw[(qd >> 3) * 36 + (qd & 7) * 4] = a;
    }
    // 32x32x32 matmul, 4x4 lane tile (DS in-order within wave; no barrier)
    float4 a0 = {0, 0, 0, 0}, a1 = a0, a2 = a0, a3 = a0;
#pragma unroll
    for (int kb = 0; kb < 8; kb++) {
      int k4 = kb * 4;
      float4 t0 = *(const float4*)&tw[(i0 + 0) * 36 + k4];
      float4 t1 = *(const float4*)&tw[(i0 + 1) * 36 + k4];
      float4 t2 = *(const float4*)&tw[(i0 + 2) * 36 + k4];
      float4 t3 = *(const float4*)&tw[(i0 + 3) * 36 + k4];
      float4 b0 = *(const float4*)&aw[(k4 + 0) * 36 + j0];
      float4 b1 = *(const float4*)&aw[(k4 + 1) * 36 + j0];
      float4 b2 = *(const float4*)&aw[(k4 + 2) * 36 + j0];
      float4 b3 = *(const float4*)&aw[(k4 + 3) * 36 + j0];
      a0.x += t0.x * b0.x; a0.y += t0.x * b0.y; a0.z += t0.x * b0.z; a0.w += t0.x * b0.w;
      a0.x += t0.y * b1.x; a0.y += t0.y * b1.y; a0.z += t0.y * b1.z; a0.w += t0.y * b1.w;
      a0.x += t0.z * b2.x; a0.y += t0.z * b2.y; a0.z += t0.z * b2.z; a0.w += t0.z * b2.w;
      a0.x += t0.w * b3.x; a0.y += t0.w * b3.y; a0.z += t0.w * b3.z; a0.w += t0.w * b3.w;
      a1.x += t1.x * b0.x; a1.y += t1.x * b0.y; a1.z += t1.x * b0.z; a1.w += t1.x * b0.w;
      a1.x += t1.y * b1.x; a1.y += t1.y * b1.y; a1.z += t1.y * b1.z; a1.w += t1.y * b1.w;
      a1.x += t1.z * b2.x; a1.y += t1.z * b2.y; a1.z += t1.z * b2.z; a1.w += t1.z * b2.w;
      a1.x += t1.w * b3.x; a1.y += t1.w * b3.y; a1.z += t1.w * b3.z; a1.w += t1.w * b3.w;
      a2.x += t2.x * b0.x; a2.y += t2.x * b0.y; a2.z += t2.x * b0.z; a2.w += t2.x * b0.w;
      a2.x += t2.y * b1.x; a2.y += t2.y * b1.y; a2.z += t2.y * b1.z; a2.w += t2.y * b1.w;
      a2.x += t2.z * b2.x; a2.y += t2.z * b2.y; a2.z += t2.z * b2.z; a2.w += t2.z * b2.w;
      a2.x += t2.w * b3.x; a2.y += t2.w * b3.y; a2.z += t2.w * b3.z; a2.w += t2.w * b3.w;
      a3.x += t3.x * b0.x; a3.y += t3.x * b0.y; a3.z += t3.x * b0.z; a3.w += t3.x * b0.w;
      a3.x += t3.y * b1.x; a3.y += t3.y * b1.y; a3.z += t3.y * b1.z; a3.w += t3.y * b1.w;
      a3.x += t3.z * b2.x; a3.y += t3.z * b2.y; a3.z += t3.z * b2.z; a3.w += t3.z * b2.w;
      a3.x += t3.w * b3.x; a3.y += t3.w * b3.y; a3.z += t3.w * b3.z; a3.w += t3.w * b3.w;
    }
    // residual RMW into X plane
    float* xr = Xp + (((size_t)(g * 128 + h)) << 10);
    float4* r0 = (float4*)&xr[(i0 + 0) * 32 + j0];
    float4* r1 = (float4*)&xr[(i0 + 1) * 32 + j0];
    float4* r2 = (float4*)&xr[(i0 + 2) * 32 + j0];
    float4* r3 = (float4*)&xr[(i0 + 3) * 32 + j0];
    float4 x0 = *r0, x1 = *r1, x2 = *r2, x3 = *r3;
    x0.x += a0.x; x0.y += a0.y; x0.z += a0.z; x0.w += a0.w;
    x1.x += a1.x; x1.y += a1.y; x1.z += a1.z; x1.w += a1.w;
    x2.x += a2.x; x2.y += a2.y; x2.z += a2.z; x2.w += a2.w;
    x3.x += a3.x; x3.y += a3.y; x3.z += a3.z; x3.w += a3.w;
    *r0 = x0; *r1 = x1; *r2 = x2; *r3 = x3;
  }
}

// ---------------------------------------------------------------------------
// T: pool(mean over j) -> @Wp+bp -> LN -> relu -> sum over i -> @Wq1+bq1 ->
//    LN -> relu -> @Wq2+bq2.  One WG per graph.
// ---------------------------------------------------------------------------
__global__ __launch_bounds__(256) void k_tail(
    const float* __restrict__ Xp,
    const float* __restrict__ Wp, const float* __restrict__ bp,
    const float* __restrict__ gp, const float* __restrict__ cp,
    const float* __restrict__ Wq1, const float* __restrict__ bq1,
    const float* __restrict__ gq1, const float* __restrict__ cq1,
    const float* __restrict__ Wq2, const float* __restrict__ bq2,
    float* __restrict__ out) {
  int g = blockIdx.x, tid = threadIdx.x;
  __shared__ float xs_s[32 * 132];
  __shared__ float y_s[32 * 132];
  __shared__ float stat_m[32], stat_r[32];
  __shared__ float hg_s[128];
  __shared__ float q_s[128];
  __shared__ float redf[128];
  const float* Xg = Xp + ((size_t)g << 17);
#pragma unroll
  for (int m = 0; m < 16; m++) {
    int rid = m * 256 + tid;
    int hh = rid >> 5, ii = rid & 31;
    const float4* src = (const float4*)(Xg + (size_t)hh * 1024 + ii * 32);
    float s = 0.f;
#pragma unroll
    for (int q = 0; q < 8; q++) { float4 v = src[q]; s += (v.x + v.y) + (v.z + v.w); }
    xs_s[ii * 132 + hh] = s * (1.f / 32.f);
  }
  __syncthreads();
  int i_ = tid >> 3, h0 = (tid & 7) * 16;
  float acc[16];
#pragma unroll
  for (int hh = 0; hh < 16; hh++) acc[hh] = bp[h0 + hh];
  for (int k = 0; k < 128; k++) {
    float a = xs_s[i_ * 132 + k];
    const float4* wr = (const float4*)(Wp + k * 128 + h0);
    float4 w0 = wr[0], w1 = wr[1], w2 = wr[2], w3 = wr[3];
    acc[0]  += a * w0.x; acc[1]  += a * w0.y; acc[2]  += a * w0.z; acc[3]  += a * w0.w;
    acc[4]  += a * w1.x; acc[5]  += a * w1.y; acc[6]  += a * w1.z; acc[7]  += a * w1.w;
    acc[8]  += a * w2.x; acc[9]  += a * w2.y; acc[10] += a * w2.z; acc[11] += a * w2.w;
    acc[12] += a * w3.x; acc[13] += a * w3.y; acc[14] += a * w3.z; acc[15] += a * w3.w;
  }
#pragma unroll
  for (int hh = 0; hh < 16; hh++) y_s[i_ * 132 + h0 + hh] = acc[hh];
  __syncthreads();
  if (tid < 32) {
    float s = 0.f;
    for (int hh = 0; hh < 128; hh++) s += y_s[tid * 132 + hh];
    float m = s * (1.f / 128.f);
    float q = 0.f;
    for (int hh = 0; hh < 128; hh++) { float d = y_s[tid * 132 + hh] - m; q += d * d; }
    stat_m[tid] = m;
    stat_r[tid] = rsqrtf(q * (1.f / 128.f) + 1e-5f);
  }
  __syncthreads();
  {
    float m = stat_m[i_], r = stat_r[i_];
#pragma unroll
    for (int hh = 0; hh < 16; hh++) {
      int hcol = h0 + hh;
      float v = (y_s[i_ * 132 + hcol] - m) * r * gp[hcol] + cp[hcol];
      y_s[i_ * 132 + hcol] = fmaxf(v, 0.f);
    }
  }
  __syncthreads();
  if (tid < 128) {
    float s = 0.f;
#pragma unroll
    for (int ii = 0; ii < 32; ii++) s += y_s[ii * 132 + tid];
    hg_s[tid] = s;
  }
  __syncthreads();
  if (tid < 128) {
    float a = bq1[tid];
    for (int k = 0; k < 128; k++) a += hg_s[k] * Wq1[k * 128 + tid];
    q_s[tid] = a;
  }
  __syncthreads();
  if (tid == 0) {
    float s = 0.f;
    for (int k = 0; k < 128; k++) s += q_s[k];
    float m = s * (1.f / 128.f);
    float q = 0.f;
    for (int k = 0; k < 128; k++) { float d = q_s[k] - m; q += d * d; }
    stat_m[0] = m;
    stat_r[0] = rsqrtf(q * (1.f / 128.f) + 1e-5f);
  }
  __syncthreads();
  if (tid < 128) {
    float v = (q_s[tid] - stat_m[0]) * stat_r[0] * gq1[tid] + cq1[tid];
    v = fmaxf(v, 0.f);
    redf[tid] = v * Wq2[tid];
  }
  __syncthreads();
  if (tid == 0) {
    float s = 0.f;
    for (int k = 0; k < 128; k++) s += redf[k];
    out[g] = s + bq2[0];
  }
}

// ---------------------------------------------------------------------------
extern "C" void kernel_launch(void* const* d_in, const int* in_sizes, int n_in,
                              void* d_out, int out_size, void* d_ws, size_t ws_size,
                              hipStream_t stream) {
  const int*   x_idx  = (const int*)d_in[0];
  const int*   ea_idx = (const int*)d_in[1];
  const int*   tf_idx = (const int*)d_in[2];
  const int*   adj    = (const int*)d_in[3];
  const float* emb_x  = (const float*)d_in[4];
  const float* emb_ea = (const float*)d_in[5];
  const float* emb_tf = (const float*)d_in[6];
  const float* W0  = (const float*)d_in[7];
  const float* b0  = (const float*)d_in[8];
  const float* W1  = (const float*)d_in[9];
  const float* b1  = (const float*)d_in[10];
  const float* Wc  = (const float*)d_in[11];
  const float* bc  = (const float*)d_in[12];
  const float* gc  = (const float*)d_in[13];
  const float* cc  = (const float*)d_in[14];
  const float* Wp  = (const float*)d_in[15];
  const float* bp  = (const float*)d_in[16];
  const float* gp  = (const float*)d_in[17];
  const float* cp  = (const float*)d_in[18];
  const float* Wq1 = (const float*)d_in[19];
  const float* bq1 = (const float*)d_in[20];
  const float* gq1 = (const float*)d_in[21];
  const float* cq1 = (const float*)d_in[22];
  const float* Wq2 = (const float*)d_in[23];
  const float* bq2 = (const float*)d_in[24];
  float* out = (float*)d_out;

  float* ws  = (float*)d_ws;
  float* Xp  = ws;
  float* tXp = ws + (size_t)16777216;
  float* P0  = ws + (size_t)33554432;
  float* P1  = P0 + 4096;

  k_emb_mm<<<2, 256, 0, stream>>>(emb_x, W0, b0, P0, W1, b1, P1);
  k_buildX<<<G, 256, 0, stream>>>(x_idx, tf_idx, P0, P1, emb_tf, Xp);
  for (int l = 0; l < L; l++) {
    k_conv_mlp<<<G * 4, 256, 0, stream>>>(Xp, Wc + (size_t)l * H * H,
                                          bc + l * H, gc + l * H, cc + l * H, tXp);
    k_conv_msg<<<G * 16, 256, 0, stream>>>(tXp, ea_idx, adj, emb_ea, Xp);
  }
  k_tail<<<G, 256, 0, stream>>>(Xp, Wp, bp, gp, cp, Wq1, bq1, gq1, cq1, Wq2, bq2, out);
}

// Round 3
// 661.414 us; speedup vs baseline: 5.2348x; 5.2348x over previous
//
#include <hip/hip_runtime.h>

#define G 128
#define N 32
#define H 128
#define L 6

typedef _Float16 half8 __attribute__((ext_vector_type(8)));
typedef float f32x4 __attribute__((ext_vector_type(4)));

union H8 { unsigned u[4]; half8 v; };

__device__ inline unsigned short f16_bits(_Float16 h) {
  union { _Float16 f; unsigned short u; } c; c.f = h; return c.u;
}

// pack fp32 -> (f16 hi) | (f16 lo)<<16, hi = rne(x), lo = rne(x - hi)
__device__ inline unsigned packf16(float x) {
  _Float16 hi = (_Float16)x;
  _Float16 lo = (_Float16)(x - (float)hi);
  return (unsigned)f16_bits(hi) | ((unsigned)f16_bits(lo) << 16);
}

// ---------------------------------------------------------------------------
// E1: P0 = emb_x @ W0 + b0, P1 = emb_x @ W1 + b1. grid=2.
// ---------------------------------------------------------------------------
__global__ __launch_bounds__(256) void k_emb_mm(
    const float* __restrict__ emb_x,
    const float* __restrict__ W0, const float* __restrict__ b0, float* __restrict__ P0,
    const float* __restrict__ W1, const float* __restrict__ b1, float* __restrict__ P1) {
  const float* W = blockIdx.x ? W1 : W0;
  const float* b = blockIdx.x ? b1 : b0;
  float*       P = blockIdx.x ? P1 : P0;
  __shared__ float embs_t[128 * 32];   // [k][i]
  int tid = threadIdx.x;
  {
    int i = tid & 31, k0 = (tid >> 5) * 16;
    const float* src = emb_x + i * 128 + k0;
#pragma unroll
    for (int m = 0; m < 16; m++) embs_t[(k0 + m) * 32 + i] = src[m];
  }
  __syncthreads();
  int i  = tid >> 3;
  int h0 = (tid & 7) * 16;
  float acc[16];
#pragma unroll
  for (int hh = 0; hh < 16; hh++) acc[hh] = b[h0 + hh];
  for (int k = 0; k < 128; k++) {
    float a = embs_t[k * 32 + i];
    const float4* wr = (const float4*)(W + k * 128 + h0);
    float4 w0 = wr[0], w1 = wr[1], w2 = wr[2], w3 = wr[3];
    acc[0]  += a * w0.x; acc[1]  += a * w0.y; acc[2]  += a * w0.z; acc[3]  += a * w0.w;
    acc[4]  += a * w1.x; acc[5]  += a * w1.y; acc[6]  += a * w1.z; acc[7]  += a * w1.w;
    acc[8]  += a * w2.x; acc[9]  += a * w2.y; acc[10] += a * w2.z; acc[11] += a * w2.w;
    acc[12] += a * w3.x; acc[13] += a * w3.y; acc[14] += a * w3.z; acc[15] += a * w3.w;
  }
  float4* dst = (float4*)(P + i * 128 + h0);
  dst[0] = make_float4(acc[0], acc[1], acc[2], acc[3]);
  dst[1] = make_float4(acc[4], acc[5], acc[6], acc[7]);
  dst[2] = make_float4(acc[8], acc[9], acc[10], acc[11]);
  dst[3] = make_float4(acc[12], acc[13], acc[14], acc[15]);
}

// ---------------------------------------------------------------------------
// E2: build X h-planar: Xp[g][h][i*32+j]. One WG per graph.
// ---------------------------------------------------------------------------
__global__ __launch_bounds__(256) void k_buildX(
    const int* __restrict__ x_idx, const int* __restrict__ tf_idx,
    const float* __restrict__ P0, const float* __restrict__ P1,
    const float* __restrict__ emb_tf, float* __restrict__ Xp) {
  int g = blockIdx.x, tid = threadIdx.x;
  __shared__ float x0t[128 * 32];
  __shared__ float x1t[128 * 32];
  __shared__ float etf[128 * 16];
  __shared__ int   tfs[1024];
  {
    int i = tid & 31, h0 = (tid >> 5) * 16;
    int r = x_idx[g * 32 + i];
    const float* s0 = P0 + r * 128 + h0;
    const float* s1 = P1 + r * 128 + h0;
#pragma unroll
    for (int m = 0; m < 16; m++) {
      x0t[(h0 + m) * 32 + i] = s0[m];
      x1t[(h0 + m) * 32 + i] = s1[m];
    }
  }
  {
    int t = tid & 15, h0 = (tid >> 4) * 8;
    const float* s = emb_tf + t * 128 + h0;
#pragma unroll
    for (int m = 0; m < 8; m++) etf[(h0 + m) * 16 + t] = s[m];
  }
  ((int4*)tfs)[tid] = ((const int4*)(tf_idx + (size_t)g * 1024))[tid];
  __syncthreads();
  int i = tid >> 3, j0 = (tid & 7) * 4;
  int t0 = tfs[i * 32 + j0 + 0], t1 = tfs[i * 32 + j0 + 1];
  int t2 = tfs[i * 32 + j0 + 2], t3 = tfs[i * 32 + j0 + 3];
  float* outg = Xp + ((size_t)g << 17);
  for (int h = 0; h < 128; h++) {
    float a = x0t[h * 32 + i];
    const float* x1r = x1t + h * 32;
    const float* er  = etf + h * 16;
    float4 v;
    v.x = a * x1r[j0 + 0] * er[t0];
    v.y = a * x1r[j0 + 1] * er[t1];
    v.z = a * x1r[j0 + 2] * er[t2];
    v.w = a * x1r[j0 + 3] * er[t3];
    *(float4*)(outg + h * 1024 + tid * 4) = v;
  }
}

// ---------------------------------------------------------------------------
// K1 v4 (MFMA): tXp = relu(LN(X @ Wc[l] + bc[l])), h-planar.
// f16 hi/lo split, 3x mfma_f32_16x16x32_f16 per tile (error ~2^-22 rel).
// A = W^T (m=h), B = X native [k][p] (n=p), D -> h-planar out directly.
// LDS: packed (hi|lo<<16) words, [row][32k] with 4-word XOR swizzle
// ((k>>2)^((row>>2)&7)) -> conflict-free b128 staging writes + b64 frag reads.
// Per wave: 4 p-tiles x 8 h-tiles, 32 f32x4 MFMA accumulators. LN via
// in-register quad butterflies (shfl_xor 16/32). grid = G*4.
// ---------------------------------------------------------------------------
__global__ __launch_bounds__(256, 2) void k_conv_mlp(
    const float* __restrict__ Xp, const float* __restrict__ W,
    const float* __restrict__ bcl, const float* __restrict__ gcl,
    const float* __restrict__ ccl, float* __restrict__ tXp) {
  int g = blockIdx.x >> 2, qb = blockIdx.x & 3;
  int tid = threadIdx.x;
  __shared__ unsigned Xs[256 * 32];   // [p][k-swizzled] packed pairs
  __shared__ unsigned Ws[128 * 32];   // [h][k-swizzled] packed pairs (W^T)
  int lane = tid & 63, wv = tid >> 6;
  int x = lane & 15, quad = lane >> 4;

  // accumulators [p-tile][h-tile], init with bias bc[h], h = hh*16+quad*4+r
  f32x4 acc[4][8];
#pragma unroll
  for (int hh = 0; hh < 8; hh++) {
    float4 b4 = *(const float4*)(bcl + hh * 16 + quad * 4);
    f32x4 bi; bi[0] = b4.x; bi[1] = b4.y; bi[2] = b4.z; bi[3] = b4.w;
#pragma unroll
    for (int pt = 0; pt < 4; pt++) acc[pt][hh] = bi;
  }

  const float* Xg = Xp + ((size_t)g << 17) + qb * 256;

  for (int c = 0; c < 4; c++) {
    __syncthreads();   // previous chunk's fragment reads complete
    // ---- stage X chunk (32 k-rows x 256 p), wave wv does k-rows wv*8..+7
    {
      unsigned pk[8][4];
#pragma unroll
      for (int m = 0; m < 8; m++) {
        float4 v = *(const float4*)(Xg + (size_t)(c * 32 + wv * 8 + m) * 1024 + lane * 4);
        pk[m][0] = packf16(v.x); pk[m][1] = packf16(v.y);
        pk[m][2] = packf16(v.z); pk[m][3] = packf16(v.w);
      }
#pragma unroll
      for (int r = 0; r < 4; r++) {
        int p = 4 * lane + r;
        int sw = (p >> 2) & 7;          // = lane & 7
#pragma unroll
        for (int B2 = 0; B2 < 2; B2++) {
          int B = wv * 2 + B2;          // k-block (4 words) within chunk
          uint4 q4;
          q4.x = pk[B2 * 4 + 0][r]; q4.y = pk[B2 * 4 + 1][r];
          q4.z = pk[B2 * 4 + 2][r]; q4.w = pk[B2 * 4 + 3][r];
          *(uint4*)&Xs[p * 32 + ((B ^ sw) << 2)] = q4;
        }
      }
    }
    // ---- stage W chunk transposed: Ws[h][k] = W[c*32+k][h]
    {
#pragma unroll
      for (int m = 0; m < 4; m++) {
        int f4 = m * 64 + lane;
        int kk = wv * 8 + (f4 >> 5);
        int h4 = (f4 & 31) * 4;
        float4 v = *(const float4*)(W + (size_t)(c * 32 + kk) * 128 + h4);
        int Bk = kk >> 2, km = kk & 3;
#pragma unroll
        for (int j = 0; j < 4; j++) {
          float vv = j == 0 ? v.x : (j == 1 ? v.y : (j == 2 ? v.z : v.w));
          int h = h4 + j;
          Ws[h * 32 + (((Bk ^ ((h >> 2) & 7)) << 2) + km)] = packf16(vv);
        }
      }
    }
    __syncthreads();
    // ---- B fragment pairs for the 4 p-tiles
    H8 bh[4], bl[4];
#pragma unroll
    for (int pt = 0; pt < 4; pt++) {
      int p = wv * 64 + pt * 16 + x;
      int sw = (p >> 2) & 7;
#pragma unroll
      for (int n = 0; n < 4; n++) {
        int k = quad * 8 + n * 2;
        uint2 d = *(const uint2*)&Xs[p * 32 + (((k >> 2) ^ sw) << 2) + (k & 3)];
        bh[pt].u[n] = __builtin_amdgcn_perm(d.y, d.x, 0x05040100u);
        bl[pt].u[n] = __builtin_amdgcn_perm(d.y, d.x, 0x07060302u);
      }
    }
    // ---- stream A pairs over 8 h-tiles, 3 MFMA per tile
#pragma unroll
    for (int hh = 0; hh < 8; hh++) {
      H8 ah, al;
      int hrow = hh * 16 + x;
      int sw = (hrow >> 2) & 7;
#pragma unroll
      for (int n = 0; n < 4; n++) {
        int k = quad * 8 + n * 2;
        uint2 d = *(const uint2*)&Ws[hrow * 32 + (((k >> 2) ^ sw) << 2) + (k & 3)];
        ah.u[n] = __builtin_amdgcn_perm(d.y, d.x, 0x05040100u);
        al.u[n] = __builtin_amdgcn_perm(d.y, d.x, 0x07060302u);
      }
#pragma unroll
      for (int pt = 0; pt < 4; pt++) {
        acc[pt][hh] = __builtin_amdgcn_mfma_f32_16x16x32_f16(ah.v, bh[pt].v, acc[pt][hh], 0, 0, 0);
        acc[pt][hh] = __builtin_amdgcn_mfma_f32_16x16x32_f16(ah.v, bl[pt].v, acc[pt][hh], 0, 0, 0);
        acc[pt][hh] = __builtin_amdgcn_mfma_f32_16x16x32_f16(al.v, bh[pt].v, acc[pt][hh], 0, 0, 0);
      }
    }
  }

  // ---- LN over h (two-pass, in registers + quad butterflies) ----
  float gm[4], gr[4];
#pragma unroll
  for (int pt = 0; pt < 4; pt++) {
    float s = 0.f;
#pragma unroll
    for (int hh = 0; hh < 8; hh++)
#pragma unroll
      for (int r = 0; r < 4; r++) s += acc[pt][hh][r];
    s += __shfl_xor(s, 16);
    s += __shfl_xor(s, 32);
    float m = s * (1.f / 128.f);
    float qv = 0.f;
#pragma unroll
    for (int hh = 0; hh < 8; hh++)
#pragma unroll
      for (int r = 0; r < 4; r++) { float d = acc[pt][hh][r] - m; qv += d * d; }
    qv += __shfl_xor(qv, 16);
    qv += __shfl_xor(qv, 32);
    gm[pt] = m;
    gr[pt] = rsqrtf(qv * (1.f / 128.f) + 1e-5f);
  }
  // ---- normalize + relu + store ----
  int pbase = qb * 256 + wv * 64;
#pragma unroll
  for (int hh = 0; hh < 8; hh++) {
    float4 g4 = *(const float4*)(gcl + hh * 16 + quad * 4);
    float4 c4 = *(const float4*)(ccl + hh * 16 + quad * 4);
    float ga[4] = {g4.x, g4.y, g4.z, g4.w};
    float ca[4] = {c4.x, c4.y, c4.z, c4.w};
#pragma unroll
    for (int r = 0; r < 4; r++) {
      int h = hh * 16 + quad * 4 + r;
      float* dst = tXp + (((size_t)(g * 128 + h)) << 10) + pbase + x;
#pragma unroll
      for (int pt = 0; pt < 4; pt++) {
        float v = (acc[pt][hh][r] - gm[pt]) * gr[pt] * ga[r] + ca[r];
        dst[pt * 16] = fmaxf(v, 0.f);
      }
    }
  }
}

// ---------------------------------------------------------------------------
// K2 v3 (unchanged, verified round 2): X[g,h,i,j] += sum_k tX * A. 8 h-planes
// per WG (grid G*16), 2 per wave; A from packed codes; 4x4 lane tile.
// ---------------------------------------------------------------------------
__global__ __launch_bounds__(256, 4) void k_conv_msg(
    const float* __restrict__ tXp, const int* __restrict__ ea_idx,
    const int* __restrict__ adj, const float* __restrict__ emb_ea,
    float* __restrict__ Xp) {
  int g  = blockIdx.x >> 4;
  int hb = (blockIdx.x & 15) * 8;
  int tid = threadIdx.x, wv = tid >> 6, lane = tid & 63;
  __shared__ unsigned char c8[1024];
  __shared__ float eacs[8][20];
  __shared__ __align__(16) float tXs[4][32 * 36];
  __shared__ __align__(16) float As[4][32 * 36];
  {
    int4 ev = ((const int4*)(ea_idx + (size_t)g * 1024))[tid];
    int4 av = ((const int4*)(adj   + (size_t)g * 1024))[tid];
    uchar4 c;
    c.x = av.x ? (unsigned char)ev.x : (unsigned char)16;
    c.y = av.y ? (unsigned char)ev.y : (unsigned char)16;
    c.z = av.z ? (unsigned char)ev.z : (unsigned char)16;
    c.w = av.w ? (unsigned char)ev.w : (unsigned char)16;
    ((uchar4*)c8)[tid] = c;
  }
  if (tid < 128) {
    int hh = tid >> 4, e = tid & 15;
    eacs[hh][e] = emb_ea[e * 128 + hb + hh];
  }
  if (tid >= 128 && tid < 136) eacs[tid - 128][16] = 0.f;
  __syncthreads();
  int i0 = (lane >> 3) * 4, j0 = (lane & 7) * 4;
  float* tw = tXs[wv];
  float* aw = As[wv];
#pragma unroll 1
  for (int pl = 0; pl < 2; pl++) {
    int hh = wv * 2 + pl;
    int h  = hb + hh;
    const float4* tp = (const float4*)(tXp + (((size_t)(g * 128 + h)) << 10));
#pragma unroll
    for (int m = 0; m < 4; m++) {
      int f = lane + 64 * m;
      float4 v = tp[f];
      *(float4*)&tw[(f >> 3) * 36 + (f & 7) * 4] = v;
    }
#pragma unroll
    for (int m = 0; m < 4; m++) {
      int qd = lane + 64 * m;
      uchar4 cc = ((const uchar4*)c8)[qd];
      float4 a;
      a.x = eacs[hh][cc.x]; a.y = eacs[hh][cc.y];
      a.z = eacs[hh][cc.z]; a.w = eacs[hh][cc.w];
      *(float4*)&aw[(qd >> 3) * 36 + (qd & 7) * 4] = a;
    }
    float4 a0 = {0, 0, 0, 0}, a1 = a0, a2 = a0, a3 = a0;
#pragma unroll
    for (int kb = 0; kb < 8; kb++) {
      int k4 = kb * 4;
      float4 t0 = *(const float4*)&tw[(i0 + 0) * 36 + k4];
      float4 t1 = *(const float4*)&tw[(i0 + 1) * 36 + k4];
      float4 t2 = *(const float4*)&tw[(i0 + 2) * 36 + k4];
      float4 t3 = *(const float4*)&tw[(i0 + 3) * 36 + k4];
      float4 b0 = *(const float4*)&aw[(k4 + 0) * 36 + j0];
      float4 b1 = *(const float4*)&aw[(k4 + 1) * 36 + j0];
      float4 b2 = *(const float4*)&aw[(k4 + 2) * 36 + j0];
      float4 b3 = *(const float4*)&aw[(k4 + 3) * 36 + j0];
      a0.x += t0.x * b0.x; a0.y += t0.x * b0.y; a0.z += t0.x * b0.z; a0.w += t0.x * b0.w;
      a0.x += t0.y * b1.x; a0.y += t0.y * b1.y; a0.z += t0.y * b1.z; a0.w += t0.y * b1.w;
      a0.x += t0.z * b2.x; a0.y += t0.z * b2.y; a0.z += t0.z * b2.z; a0.w += t0.z * b2.w;
      a0.x += t0.w * b3.x; a0.y += t0.w * b3.y; a0.z += t0.w * b3.z; a0.w += t0.w * b3.w;
      a1.x += t1.x * b0.x; a1.y += t1.x * b0.y; a1.z += t1.x * b0.z; a1.w += t1.x * b0.w;
      a1.x += t1.y * b1.x; a1.y += t1.y * b1.y; a1.z += t1.y * b1.z; a1.w += t1.y * b1.w;
      a1.x += t1.z * b2.x; a1.y += t1.z * b2.y; a1.z += t1.z * b2.z; a1.w += t1.z * b2.w;
      a1.x += t1.w * b3.x; a1.y += t1.w * b3.y; a1.z += t1.w * b3.z; a1.w += t1.w * b3.w;
      a2.x += t2.x * b0.x; a2.y += t2.x * b0.y; a2.z += t2.x * b0.z; a2.w += t2.x * b0.w;
      a2.x += t2.y * b1.x; a2.y += t2.y * b1.y; a2.z += t2.y * b1.z; a2.w += t2.y * b1.w;
      a2.x += t2.z * b2.x; a2.y += t2.z * b2.y; a2.z += t2.z * b2.z; a2.w += t2.z * b2.w;
      a2.x += t2.w * b3.x; a2.y += t2.w * b3.y; a2.z += t2.w * b3.z; a2.w += t2.w * b3.w;
      a3.x += t3.x * b0.x; a3.y += t3.x * b0.y; a3.z += t3.x * b0.z; a3.w += t3.x * b0.w;
      a3.x += t3.y * b1.x; a3.y += t3.y * b1.y; a3.z += t3.y * b1.z; a3.w += t3.y * b1.w;
      a3.x += t3.z * b2.x; a3.y += t3.z * b2.y; a3.z += t3.z * b2.z; a3.w += t3.z * b2.w;
      a3.x += t3.w * b3.x; a3.y += t3.w * b3.y; a3.z += t3.w * b3.z; a3.w += t3.w * b3.w;
    }
    float* xr = Xp + (((size_t)(g * 128 + h)) << 10);
    float4* r0 = (float4*)&xr[(i0 + 0) * 32 + j0];
    float4* r1 = (float4*)&xr[(i0 + 1) * 32 + j0];
    float4* r2 = (float4*)&xr[(i0 + 2) * 32 + j0];
    float4* r3 = (float4*)&xr[(i0 + 3) * 32 + j0];
    float4 x0 = *r0, x1 = *r1, x2 = *r2, x3 = *r3;
    x0.x += a0.x; x0.y += a0.y; x0.z += a0.z; x0.w += a0.w;
    x1.x += a1.x; x1.y += a1.y; x1.z += a1.z; x1.w += a1.w;
    x2.x += a2.x; x2.y += a2.y; x2.z += a2.z; x2.w += a2.w;
    x3.x += a3.x; x3.y += a3.y; x3.z += a3.z; x3.w += a3.w;
    *r0 = x0; *r1 = x1; *r2 = x2; *r3 = x3;
  }
}

// ---------------------------------------------------------------------------
// T: pool(mean over j) -> @Wp+bp -> LN -> relu -> sum over i -> @Wq1+bq1 ->
//    LN -> relu -> @Wq2+bq2.  One WG per graph.
// ---------------------------------------------------------------------------
__global__ __launch_bounds__(256) void k_tail(
    const float* __restrict__ Xp,
    const float* __restrict__ Wp, const float* __restrict__ bp,
    const float* __restrict__ gp, const float* __restrict__ cp,
    const float* __restrict__ Wq1, const float* __restrict__ bq1,
    const float* __restrict__ gq1, const float* __restrict__ cq1,
    const float* __restrict__ Wq2, const float* __restrict__ bq2,
    float* __restrict__ out) {
  int g = blockIdx.x, tid = threadIdx.x;
  __shared__ float xs_s[32 * 132];
  __shared__ float y_s[32 * 132];
  __shared__ float stat_m[32], stat_r[32];
  __shared__ float hg_s[128];
  __shared__ float q_s[128];
  __shared__ float redf[128];
  const float* Xg = Xp + ((size_t)g << 17);
#pragma unroll
  for (int m = 0; m < 16; m++) {
    int rid = m * 256 + tid;
    int hh = rid >> 5, ii = rid & 31;
    const float4* src = (const float4*)(Xg + (size_t)hh * 1024 + ii * 32);
    float s = 0.f;
#pragma unroll
    for (int q = 0; q < 8; q++) { float4 v = src[q]; s += (v.x + v.y) + (v.z + v.w); }
    xs_s[ii * 132 + hh] = s * (1.f / 32.f);
  }
  __syncthreads();
  int i_ = tid >> 3, h0 = (tid & 7) * 16;
  float acc[16];
#pragma unroll
  for (int hh = 0; hh < 16; hh++) acc[hh] = bp[h0 + hh];
  for (int k = 0; k < 128; k++) {
    float a = xs_s[i_ * 132 + k];
    const float4* wr = (const float4*)(Wp + k * 128 + h0);
    float4 w0 = wr[0], w1 = wr[1], w2 = wr[2], w3 = wr[3];
    acc[0]  += a * w0.x; acc[1]  += a * w0.y; acc[2]  += a * w0.z; acc[3]  += a * w0.w;
    acc[4]  += a * w1.x; acc[5]  += a * w1.y; acc[6]  += a * w1.z; acc[7]  += a * w1.w;
    acc[8]  += a * w2.x; acc[9]  += a * w2.y; acc[10] += a * w2.z; acc[11] += a * w2.w;
    acc[12] += a * w3.x; acc[13] += a * w3.y; acc[14] += a * w3.z; acc[15] += a * w3.w;
  }
#pragma unroll
  for (int hh = 0; hh < 16; hh++) y_s[i_ * 132 + h0 + hh] = acc[hh];
  __syncthreads();
  if (tid < 32) {
    float s = 0.f;
    for (int hh = 0; hh < 128; hh++) s += y_s[tid * 132 + hh];
    float m = s * (1.f / 128.f);
    float q = 0.f;
    for (int hh = 0; hh < 128; hh++) { float d = y_s[tid * 132 + hh] - m; q += d * d; }
    stat_m[tid] = m;
    stat_r[tid] = rsqrtf(q * (1.f / 128.f) + 1e-5f);
  }
  __syncthreads();
  {
    float m = stat_m[i_], r = stat_r[i_];
#pragma unroll
    for (int hh = 0; hh < 16; hh++) {
      int hcol = h0 + hh;
      float v = (y_s[i_ * 132 + hcol] - m) * r * gp[hcol] + cp[hcol];
      y_s[i_ * 132 + hcol] = fmaxf(v, 0.f);
    }
  }
  __syncthreads();
  if (tid < 128) {
    float s = 0.f;
#pragma unroll
    for (int ii = 0; ii < 32; ii++) s += y_s[ii * 132 + tid];
    hg_s[tid] = s;
  }
  __syncthreads();
  if (tid < 128) {
    float a = bq1[tid];
    for (int k = 0; k < 128; k++) a += hg_s[k] * Wq1[k * 128 + tid];
    q_s[tid] = a;
  }
  __syncthreads();
  if (tid == 0) {
    float s = 0.f;
    for (int k = 0; k < 128; k++) s += q_s[k];
    float m = s * (1.f / 128.f);
    float q = 0.f;
    for (int k = 0; k < 128; k++) { float d = q_s[k] - m; q += d * d; }
    stat_m[0] = m;
    stat_r[0] = rsqrtf(q * (1.f / 128.f) + 1e-5f);
  }
  __syncthreads();
  if (tid < 128) {
    float v = (q_s[tid] - stat_m[0]) * stat_r[0] * gq1[tid] + cq1[tid];
    v = fmaxf(v, 0.f);
    redf[tid] = v * Wq2[tid];
  }
  __syncthreads();
  if (tid == 0) {
    float s = 0.f;
    for (int k = 0; k < 128; k++) s += redf[k];
    out[g] = s + bq2[0];
  }
}

// ---------------------------------------------------------------------------
extern "C" void kernel_launch(void* const* d_in, const int* in_sizes, int n_in,
                              void* d_out, int out_size, void* d_ws, size_t ws_size,
                              hipStream_t stream) {
  const int*   x_idx  = (const int*)d_in[0];
  const int*   ea_idx = (const int*)d_in[1];
  const int*   tf_idx = (const int*)d_in[2];
  const int*   adj    = (const int*)d_in[3];
  const float* emb_x  = (const float*)d_in[4];
  const float* emb_ea = (const float*)d_in[5];
  const float* emb_tf = (const float*)d_in[6];
  const float* W0  = (const float*)d_in[7];
  const float* b0  = (const float*)d_in[8];
  const float* W1  = (const float*)d_in[9];
  const float* b1  = (const float*)d_in[10];
  const float* Wc  = (const float*)d_in[11];
  const float* bc  = (const float*)d_in[12];
  const float* gc  = (const float*)d_in[13];
  const float* cc  = (const float*)d_in[14];
  const float* Wp  = (const float*)d_in[15];
  const float* bp  = (const float*)d_in[16];
  const float* gp  = (const float*)d_in[17];
  const float* cp  = (const float*)d_in[18];
  const float* Wq1 = (const float*)d_in[19];
  const float* bq1 = (const float*)d_in[20];
  const float* gq1 = (const float*)d_in[21];
  const float* cq1 = (const float*)d_in[22];
  const float* Wq2 = (const float*)d_in[23];
  const float* bq2 = (const float*)d_in[24];
  float* out = (float*)d_out;

  float* ws  = (float*)d_ws;
  float* Xp  = ws;
  float* tXp = ws + (size_t)16777216;
  float* P0  = ws + (size_t)33554432;
  float* P1  = P0 + 4096;

  k_emb_mm<<<2, 256, 0, stream>>>(emb_x, W0, b0, P0, W1, b1, P1);
  k_buildX<<<G, 256, 0, stream>>>(x_idx, tf_idx, P0, P1, emb_tf, Xp);
  for (int l = 0; l < L; l++) {
    k_conv_mlp<<<G * 4, 256, 0, stream>>>(Xp, Wc + (size_t)l * H * H,
                                          bc + l * H, gc + l * H, cc + l * H, tXp);
    k_conv_msg<<<G * 16, 256, 0, stream>>>(tXp, ea_idx, adj, emb_ea, Xp);
  }
  k_tail<<<G, 256, 0, stream>>>(Xp, Wp, bp, gp, cp, Wq1, bq1, gq1, cq1, Wq2, bq2, out);
}